// Round 8
// baseline (724.515 us; speedup 1.0000x reference)
//
#include <hip/hip_runtime.h>

#define TOKENS 8192
#define D_IN   4096
#define FEATS  16384
#define NT64   (D_IN / 64)   // 64 K-tiles of 64 (i8)

typedef __attribute__((ext_vector_type(4))) int   i4v;
typedef __attribute__((ext_vector_type(4))) float f32x4;

__device__ __forceinline__ void gload_lds16(const void* g, void* l) {
  __builtin_amdgcn_global_load_lds(
      (const __attribute__((address_space(1))) void*)g,
      (__attribute__((address_space(3))) void*)l, 16, 0, 0);
}

// ---------------- pre-pass A: x fp32 -> int8 with per-row scale ----------------
__device__ __forceinline__ int pack4(float4 f, float inv) {
  int a = __float2int_rn(f.x * inv), b = __float2int_rn(f.y * inv),
      c = __float2int_rn(f.z * inv), d = __float2int_rn(f.w * inv);
  return (a & 0xff) | ((b & 0xff) << 8) | ((c & 0xff) << 16) | ((d & 0xff) << 24);
}

__global__ __launch_bounds__(256) void quant_x_kernel(const float* __restrict__ x,
                                                      signed char* __restrict__ xq,
                                                      float* __restrict__ xs) {
  const int row = blockIdx.x, t = threadIdx.x;
  const float* xr = x + (long)row * D_IN;
  float4 v0 = *(const float4*)(xr + t * 16 + 0);
  float4 v1 = *(const float4*)(xr + t * 16 + 4);
  float4 v2 = *(const float4*)(xr + t * 16 + 8);
  float4 v3 = *(const float4*)(xr + t * 16 + 12);
  float m = 0.f;
  m = fmaxf(m, fmaxf(fmaxf(fabsf(v0.x), fabsf(v0.y)), fmaxf(fabsf(v0.z), fabsf(v0.w))));
  m = fmaxf(m, fmaxf(fmaxf(fabsf(v1.x), fabsf(v1.y)), fmaxf(fabsf(v1.z), fabsf(v1.w))));
  m = fmaxf(m, fmaxf(fmaxf(fabsf(v2.x), fabsf(v2.y)), fmaxf(fabsf(v2.z), fabsf(v2.w))));
  m = fmaxf(m, fmaxf(fmaxf(fabsf(v3.x), fabsf(v3.y)), fmaxf(fabsf(v3.z), fabsf(v3.w))));
#pragma unroll
  for (int off = 32; off >= 1; off >>= 1) m = fmaxf(m, __shfl_xor(m, off));
  __shared__ float wm[4];
  if ((t & 63) == 0) wm[t >> 6] = m;
  __syncthreads();
  m = fmaxf(fmaxf(wm[0], wm[1]), fmaxf(wm[2], wm[3]));
  m = fmaxf(m, 1e-20f);
  const float inv = 127.f / m;
  if (t == 0) xs[row] = m / 127.f;
  int4 o;
  o.x = pack4(v0, inv); o.y = pack4(v1, inv);
  o.z = pack4(v2, inv); o.w = pack4(v3, inv);
  *(int4*)(xq + (long)row * D_IN + t * 16) = o;
}

// ---------------- pre-pass B: kernel int32 [K][N] -> int8 Wq [N][K] ----------------
__global__ __launch_bounds__(256) void wtrans8_kernel(const int* __restrict__ kq,
                                                      signed char* __restrict__ wt) {
  __shared__ signed char tile[64][68];
  const int n0 = blockIdx.x * 64, k0 = blockIdx.y * 64;
  const int t = threadIdx.x;
  const int kr = t >> 4, nc = (t & 15) * 4;
#pragma unroll
  for (int p = 0; p < 4; p++) {
    int4 v = *(const int4*)(kq + (long)(k0 + kr + 16 * p) * FEATS + n0 + nc);
    tile[kr + 16 * p][nc + 0] = (signed char)v.x;
    tile[kr + 16 * p][nc + 1] = (signed char)v.y;
    tile[kr + 16 * p][nc + 2] = (signed char)v.z;
    tile[kr + 16 * p][nc + 3] = (signed char)v.w;
  }
  __syncthreads();
  const int nr = t >> 4, kc = (t & 15) * 4;
#pragma unroll
  for (int p = 0; p < 4; p++) {
    int n = nr + 16 * p;
    int o = (tile[kc + 0][n] & 0xff) | ((tile[kc + 1][n] & 0xff) << 8) |
            ((tile[kc + 2][n] & 0xff) << 16) | ((tile[kc + 3][n] & 0xff) << 24);
    *(int*)(wt + (long)(n0 + n) * D_IN + k0 + kc) = o;
  }
}

// ---------------- main GEMM: 256x128 tile, BK=64 i8, 2 blocks/CU ----------------
#define BAR        __builtin_amdgcn_s_barrier()
#define VMCNT0     asm volatile("s_waitcnt vmcnt(0)" ::: "memory")
#define PRIO1      __builtin_amdgcn_s_setprio(1)
#define PRIO0      __builtin_amdgcn_s_setprio(0)

// LDS: buf B_ in {0,1}: A tile 256x64 (16 KB) then B tile 128x64 (8 KB)
#define TILEA(B_) (smem + (B_) * 24576)
#define TILEB(B_) (smem + (B_) * 24576 + 16384)

// stage tile KT into buf B_ (3 gload_lds: A rows 0-127, A rows 128-255, B rows 0-127)
#define STAGE_ALL(B_, KT) do { if ((KT) < NT64) { \
  gload_lds16(Xq + aOff0 + (unsigned)(KT) * 64, TILEA(B_) + t16); \
  gload_lds16(Xq + aOff1 + (unsigned)(KT) * 64, TILEA(B_) + 8192 + t16); \
  gload_lds16(Wq + bOff0 + (unsigned)(KT) * 64, TILEB(B_) + t16); } } while (0)

// swizzled fragment reads: koff = (q ^ ((rl>>1)&3))*16
#define LDA1(B_, I) aF[I] = *(const i4v*)(TILEA(B_) + (wr * 64 + (I) * 16 + rl) * 64 + koff)
#define LDB1(B_, J) bF[J] = *(const i4v*)(TILEB(B_) + (wc * 64 + (J) * 16 + rl) * 64 + koff)
#define LDALL(B_) do { \
  LDA1(B_, 0); LDA1(B_, 1); LDA1(B_, 2); LDA1(B_, 3); \
  LDB1(B_, 0); LDB1(B_, 1); LDB1(B_, 2); LDB1(B_, 3); } while (0)

#define MM16 do { \
  _Pragma("unroll") for (int i = 0; i < 4; ++i) \
  _Pragma("unroll") for (int j = 0; j < 4; ++j) \
    acc[i][j] = __builtin_amdgcn_mfma_i32_16x16x64_i8(aF[i], bF[j], acc[i][j], 0, 0, 0); \
  } while (0)

// one K-tile: stage KT+? into other buf first (longest cover), then read+MFMA
#define KTILE(B_, TN) do { \
  STAGE_ALL(B_ ^ 1, TN); \
  LDALL(B_); \
  PRIO1; MM16; PRIO0; \
  VMCNT0; BAR; } while (0)

// epilogue LDS: 64 rows x pitch 132 f32 = 33792 B (reuses smem)
#define EP_PITCH 132

__global__ __launch_bounds__(512, 4) void gemm8i_kernel(
    const signed char* __restrict__ Xq,      // [M][K] i8
    const signed char* __restrict__ Wq,      // [N][K] i8
    const float* __restrict__ xs,            // [M] per-row x scale
    const float* __restrict__ scale,         // [N]
    const float* __restrict__ bias,          // [N]
    float* __restrict__ C) {
  __shared__ __attribute__((aligned(16))) char smem[49152];

  const int tid = threadIdx.x;
  const int lane = tid & 63, wid = tid >> 6;
  const int wr = wid >> 1, wc = wid & 1;       // 4 x 2 wave grid, each 64x64 out
  const int rl = lane & 15, q = lane >> 4;

  // XCD map: 4096 blocks; per XCD 4 m-tiles x 128 n-tiles, walked as
  // 4m x 16n rectangles (m-fastest) -> 64 concurrent blocks share panels in L2.
  const int bid  = blockIdx.x;
  const int xcd  = bid & 7;
  const int l    = bid >> 3;          // [0,512)
  const int rect = l >> 6;            // [0,8)
  const int r    = l & 63;
  const int mloc = r & 3;
  const int nl   = r >> 2;            // [0,16)
  const long m0 = (long)(xcd * 4 + mloc) * 256;
  const long n0 = (long)(rect * 16 + nl) * 128;

  // staging: thread t -> row t>>2, granule t&3; source pre-swizzled by
  // the read-side involution g ^= (row>>1)&3  (rule 21)
  const unsigned t16  = (unsigned)tid * 16;
  const unsigned sgb  = (unsigned)(((tid & 3) ^ ((tid >> 3) & 3)) * 16);
  const unsigned aOff0 = (unsigned)((m0 + (tid >> 2)) * D_IN) + sgb;
  const unsigned aOff1 = aOff0 + 128u * D_IN;
  const unsigned bOff0 = (unsigned)((n0 + (tid >> 2)) * D_IN) + sgb;

  // read-side swizzle
  const int koff = ((q ^ ((rl >> 1) & 3)) << 4);

  i4v acc[4][4] = {};
  i4v aF[4], bF[4];

  // ---- prologue: stage tile 0 into buf0 ----
  STAGE_ALL(0, 0);
  VMCNT0;
  BAR;

  for (int it = 0; it < NT64 / 2; ++it) {
    KTILE(0, 2 * it + 1);   // compute even tile (buf0), stage odd -> buf1
    KTILE(1, 2 * it + 2);   // compute odd tile (buf1), stage even -> buf0
  }

  // ---- epilogue: full-line C stores via LDS transpose ----
  // y = acc * xs[row] * (1/scale[col]) + bias[col]
  float rsv[4], bvv[4];
#pragma unroll
  for (int j = 0; j < 4; j++) {
    const long col = n0 + wc * 64 + j * 16 + rl;
    rsv[j] = 1.0f / scale[col];
    bvv[j] = bias[col];
  }
  float* ldsF = (float*)smem;
#pragma unroll
  for (int p = 0; p < 4; ++p) {
    if (p) BAR;                       // wait previous pass's stores
    if (wr == p) {                    // 2 waves write this 64-row stripe
#pragma unroll
      for (int i = 0; i < 4; ++i) {
        const long grow0 = m0 + p * 64 + i * 16 + q * 4;
#pragma unroll
        for (int r2 = 0; r2 < 4; ++r2) {
          const float xv = xs[grow0 + r2];
          float* dst = ldsF + (i * 16 + q * 4 + r2) * EP_PITCH + wc * 64;
#pragma unroll
          for (int j = 0; j < 4; ++j)
            dst[j * 16 + rl] = (float)acc[i][j][r2] * xv * rsv[j] + bvv[j];
        }
      }
    }
    BAR;
    // store: 512 B contiguous per 32-lane group -> full L2 lines
    const int row16 = tid >> 5;       // [0,16)
#pragma unroll
    for (int g = 0; g < 4; ++g) {
      const int row = g * 16 + row16;
      const float* src = ldsF + row * EP_PITCH + (tid & 31) * 4;
      float* dst = C + (m0 + p * 64 + row) * (long)FEATS + n0 + (tid & 31) * 4;
      *(f32x4*)dst = *(const f32x4*)src;
    }
  }
}

// ---------------- fallback (ws too small): naive fp32 tiled GEMM ----------------
__global__ void naive_kernel(const float* __restrict__ x, const int* __restrict__ kq,
                             const float* __restrict__ scale, const float* __restrict__ bias,
                             float* __restrict__ out) {
  __shared__ float xa[16][16];
  __shared__ float wb[16][17];
  const int n = blockIdx.x * 16 + threadIdx.x;
  const int m = blockIdx.y * 16 + threadIdx.y;
  float accv = 0.f;
  for (int k0 = 0; k0 < D_IN; k0 += 16) {
    xa[threadIdx.y][threadIdx.x] = x[(long)m * D_IN + k0 + threadIdx.x];
    wb[threadIdx.y][threadIdx.x] = (float)kq[(long)(k0 + threadIdx.y) * FEATS + n];
    __syncthreads();
#pragma unroll
    for (int kk = 0; kk < 16; kk++) accv += xa[threadIdx.y][kk] * wb[kk][threadIdx.x];
    __syncthreads();
  }
  out[(long)m * FEATS + n] = accv * (1.0f / scale[n]) + bias[n];
}

extern "C" void kernel_launch(void* const* d_in, const int* in_sizes, int n_in,
                              void* d_out, int out_size, void* d_ws, size_t ws_size,
                              hipStream_t stream) {
  const float* x     = (const float*)d_in[0];
  const int*   kq    = (const int*)d_in[1];
  const float* scale = (const float*)d_in[2];
  const float* bias  = (const float*)d_in[3];
  float* out = (float*)d_out;

  const size_t need = (size_t)TOKENS * D_IN + (size_t)FEATS * D_IN + TOKENS * 4;
  if (ws_size < need) {
    naive_kernel<<<dim3(FEATS / 16, TOKENS / 16), dim3(16, 16), 0, stream>>>(
        x, kq, scale, bias, out);
    return;
  }

  signed char* Xq = (signed char*)d_ws;
  signed char* Wq = Xq + (size_t)TOKENS * D_IN;
  float* xs = (float*)(Wq + (size_t)FEATS * D_IN);

  quant_x_kernel<<<TOKENS, 256, 0, stream>>>(x, Xq, xs);
  wtrans8_kernel<<<dim3(FEATS / 64, D_IN / 64), dim3(256), 0, stream>>>(kq, Wq);
  gemm8i_kernel<<<dim3((TOKENS / 256) * (FEATS / 128)), 512, 0, stream>>>(
      Xq, Wq, xs, scale, bias, out);
}

// Round 11
// 664.043 us; speedup vs baseline: 1.0911x; 1.0911x over previous
//
#include <hip/hip_runtime.h>

#define TOKENS 8192
#define D_IN   4096
#define FEATS  16384
#define NT     (D_IN / 128)  // 32 K-tiles of 128 (i8)
#define NIT    (NT / 2)      // 16 iterations, 2 K-tiles each

typedef __attribute__((ext_vector_type(4)))  int   i4v;
typedef __attribute__((ext_vector_type(16))) int   i16v;
typedef __attribute__((ext_vector_type(4)))  float f32x4;

__device__ __forceinline__ void gload_lds16(const void* g, void* l) {
  __builtin_amdgcn_global_load_lds(
      (const __attribute__((address_space(1))) void*)g,
      (__attribute__((address_space(3))) void*)l, 16, 0, 0);
}

// ---------------- pre-pass A: x fp32 -> int8 with per-row scale ----------------
__device__ __forceinline__ int pack4(float4 f, float inv) {
  int a = __float2int_rn(f.x * inv), b = __float2int_rn(f.y * inv),
      c = __float2int_rn(f.z * inv), d = __float2int_rn(f.w * inv);
  return (a & 0xff) | ((b & 0xff) << 8) | ((c & 0xff) << 16) | ((d & 0xff) << 24);
}

__global__ __launch_bounds__(256) void quant_x_kernel(const float* __restrict__ x,
                                                      signed char* __restrict__ xq,
                                                      float* __restrict__ xs) {
  const int row = blockIdx.x, t = threadIdx.x;
  const float* xr = x + (long)row * D_IN;
  float4 v0 = *(const float4*)(xr + t * 16 + 0);
  float4 v1 = *(const float4*)(xr + t * 16 + 4);
  float4 v2 = *(const float4*)(xr + t * 16 + 8);
  float4 v3 = *(const float4*)(xr + t * 16 + 12);
  float m = 0.f;
  m = fmaxf(m, fmaxf(fmaxf(fabsf(v0.x), fabsf(v0.y)), fmaxf(fabsf(v0.z), fabsf(v0.w))));
  m = fmaxf(m, fmaxf(fmaxf(fabsf(v1.x), fabsf(v1.y)), fmaxf(fabsf(v1.z), fabsf(v1.w))));
  m = fmaxf(m, fmaxf(fmaxf(fabsf(v2.x), fabsf(v2.y)), fmaxf(fabsf(v2.z), fabsf(v2.w))));
  m = fmaxf(m, fmaxf(fmaxf(fabsf(v3.x), fabsf(v3.y)), fmaxf(fabsf(v3.z), fabsf(v3.w))));
#pragma unroll
  for (int off = 32; off >= 1; off >>= 1) m = fmaxf(m, __shfl_xor(m, off));
  __shared__ float wm[4];
  if ((t & 63) == 0) wm[t >> 6] = m;
  __syncthreads();
  m = fmaxf(fmaxf(wm[0], wm[1]), fmaxf(wm[2], wm[3]));
  m = fmaxf(m, 1e-20f);
  const float inv = 127.f / m;
  if (t == 0) xs[row] = m / 127.f;
  int4 o;
  o.x = pack4(v0, inv); o.y = pack4(v1, inv);
  o.z = pack4(v2, inv); o.w = pack4(v3, inv);
  *(int4*)(xq + (long)row * D_IN + t * 16) = o;
}

// ---------------- pre-pass B: kernel int32 [K][N] -> int8 Wq [N][K] ----------------
__global__ __launch_bounds__(256) void wtrans8_kernel(const int* __restrict__ kq,
                                                      signed char* __restrict__ wt) {
  __shared__ signed char tile[64][68];
  const int n0 = blockIdx.x * 64, k0 = blockIdx.y * 64;
  const int t = threadIdx.x;
  const int kr = t >> 4, nc = (t & 15) * 4;
#pragma unroll
  for (int p = 0; p < 4; p++) {
    int4 v = *(const int4*)(kq + (long)(k0 + kr + 16 * p) * FEATS + n0 + nc);
    tile[kr + 16 * p][nc + 0] = (signed char)v.x;
    tile[kr + 16 * p][nc + 1] = (signed char)v.y;
    tile[kr + 16 * p][nc + 2] = (signed char)v.z;
    tile[kr + 16 * p][nc + 3] = (signed char)v.w;
  }
  __syncthreads();
  const int nr = t >> 4, kc = (t & 15) * 4;
#pragma unroll
  for (int p = 0; p < 4; p++) {
    int n = nr + 16 * p;
    int o = (tile[kc + 0][n] & 0xff) | ((tile[kc + 1][n] & 0xff) << 8) |
            ((tile[kc + 2][n] & 0xff) << 16) | ((tile[kc + 3][n] & 0xff) << 24);
    *(int*)(wt + (long)(n0 + n) * D_IN + k0 + kc) = o;
  }
}

// ---------------- main GEMM: 256x256 tile, BK=128 i8, 32x32x32 MFMA, r6 schedule ----------------
#define BAR        __builtin_amdgcn_s_barrier()
#define VMCNT6     asm volatile("s_waitcnt vmcnt(6)" ::: "memory")
#define VMCNT0     asm volatile("s_waitcnt vmcnt(0)" ::: "memory")
#define PRIO1      __builtin_amdgcn_s_setprio(1)
#define PRIO0      __builtin_amdgcn_s_setprio(0)

// tile bases inside smem: buf B_ in {0,1}, MAT 0=A 1=B; each tile 256x128 B
#define TILEBASE(B_, MAT) (smem + (B_) * 65536 + (MAT) * 32768)

// stage one 64-row quarter (8 KiB) of A or B for K-tile KT into buf B_
#define STAGE_A(B_, R0, KT) do { if ((KT) < NT) \
  gload_lds16(Xq + (m0 + (R0) + sr) * (long)D_IN + (long)(KT) * 128 + sgb, \
              TILEBASE(B_, 0) + (R0) * 128 + wid * 1024); } while (0)
#define STAGE_B(B_, R0, KT) do { if ((KT) < NT) \
  gload_lds16(Wq + (n0 + (R0) + sr) * (long)D_IN + (long)(KT) * 128 + sgb, \
              TILEBASE(B_, 1) + (R0) * 128 + wid * 1024); } while (0)

// 32x32 fragment reads: A frag (mIh, ks): row = wr*128 + H*64 + mIh*32 + rl5,
// 16 k-bytes at kof[ks] (pre-XOR'd with row&7 swizzle; row offsets are x32 so row&7==rl5&7)
#define LDA_H(B_, H) do { \
  _Pragma("unroll") for (int _m = 0; _m < 2; ++_m) \
  _Pragma("unroll") for (int _k = 0; _k < 4; ++_k) \
    aF[_m][_k] = *(const i4v*)(TILEBASE(B_, 0) + \
        (wr * 128 + (H) * 64 + _m * 32 + rl5) * 128 + kof[_k]); } while (0)
#define LDB_ALL(B_) do { \
  _Pragma("unroll") for (int _n = 0; _n < 2; ++_n) \
  _Pragma("unroll") for (int _k = 0; _k < 4; ++_k) \
    bF[_n][_k] = *(const i4v*)(TILEBASE(B_, 1) + \
        (wc * 64 + _n * 32 + rl5) * 128 + kof[_k]); } while (0)

// one quadrant cluster: 8 x mfma_i32_32x32x32_i8 (ks-inner for dep distance)
#define MM8(H, J) do { \
  _Pragma("unroll") for (int _k = 0; _k < 4; ++_k) { \
    acc[(H)*2+0][J] = __builtin_amdgcn_mfma_i32_32x32x32_i8(aF[0][_k], bF[J][_k], acc[(H)*2+0][J], 0, 0, 0); \
    acc[(H)*2+1][J] = __builtin_amdgcn_mfma_i32_32x32x32_i8(aF[1][_k], bF[J][_k], acc[(H)*2+1][J], 0, 0, 0); \
  } } while (0)

// epilogue LDS layout: 2 halves x 64 rows x pitch 1040B (260 f32) = 133120 B
#define EP_PITCH 260
#define EP_HALF  (64 * EP_PITCH)

__global__ __launch_bounds__(512, 2) void gemm8i_kernel(
    const signed char* __restrict__ Xq,      // [M][K] i8
    const signed char* __restrict__ Wq,      // [N][K] i8
    const float* __restrict__ xs,            // [M] per-row x scale
    const float* __restrict__ scale,         // [N]
    const float* __restrict__ bias,          // [N]
    float* __restrict__ C) {
  // max(main 131072, epilogue 133120)
  __shared__ __attribute__((aligned(16))) char smem[133120];

  const int tid = threadIdx.x;
  const int lane = tid & 63, wid = tid >> 6;
  const int wr = wid >> 2, wc = wid & 3;       // 2 x 4 wave grid, each 128x64 out
  const int rl5 = lane & 31, hi = lane >> 5;

  // L2-sharing map: per-XCD resident set = 4m x 8n rectangle (m-fastest)
  const int bid  = blockIdx.x;
  const int xcd  = bid & 7;
  const int l    = bid >> 3;          // [0,256)
  const int rect = l >> 5;            // [0,8)  n-octant
  const int r    = l & 31;
  const int mloc = r & 3;
  const int nl   = r >> 2;            // [0,8)
  const long m0 = (long)(xcd * 4 + mloc) * 256;
  const long n0 = (long)(rect * 8 + nl) * 256;

  // staging: thread t covers row sr, 16B granule (t&7), source pre-swizzled (rule 21)
  const int sr = tid >> 3;
  const int sgb = ((tid & 7) ^ (sr & 7)) * 16;  // byte offset within 128B row

  // read-side swizzle: 16 k-bytes of (ks, lane-half) at byte (ks*32+hi*16) ^ ((row&7)<<4)
  const int xm = (lane & 7) << 4;
  int kof[4];
#pragma unroll
  for (int _k = 0; _k < 4; ++_k) kof[_k] = ((_k << 5) | (hi << 4)) ^ xm;

  i16v acc[4][2] = {};   // [mI][nJ], 16 i32 each: col=lane&31, row=(rg&3)+8*(rg>>2)+4*hi
  i4v aF[2][4], bF[2][4];

  // ---- prologue: tile0 full (8 quarters) + tile1 {B x4, A-q0, A-q2} (6) ----
  STAGE_B(0, 0, 0); STAGE_B(0, 64, 0); STAGE_B(0, 128, 0); STAGE_B(0, 192, 0);
  STAGE_A(0, 0, 0); STAGE_A(0, 64, 0); STAGE_A(0, 128, 0); STAGE_A(0, 192, 0);
  STAGE_B(1, 0, 1); STAGE_B(1, 64, 1); STAGE_B(1, 128, 1); STAGE_B(1, 192, 1);
  STAGE_A(1, 0, 1); STAGE_A(1, 128, 1);
  VMCNT6;   // tile0's 8 landed; tile1's 6 in flight
  BAR;

  // r6 schedule: clumped reads {16,0,8,0}, 1 barrier/phase, vmcnt6 at ph3/ph7.
  // Stage plan: ph0: t1 A-q1,q3 | ph1: t2 A-q0,q2 | ph2: t2 B-q0,q1
  //             ph3: t2 B-q2,q3 | ph4: t2 A-q1,q3 | ph5: t3 A-q0,q2
  //             ph6: t3 B-q0,q1 | ph7: t3 B-q2,q3
  for (int it = 0; it < NIT; ++it) {
    const int t1 = 2 * it + 1, t2 = 2 * it + 2, t3 = 2 * it + 3;
    // ph0: reads aF-H0 (8) + bF all (8); MM(0,0)
    LDA_H(0, 0); LDB_ALL(0);
    STAGE_A(1, 64, t1); STAGE_A(1, 192, t1);
    PRIO1; MM8(0, 0); PRIO0; BAR;
    // ph1: no reads; MM(0,1)
    STAGE_A(0, 0, t2); STAGE_A(0, 128, t2);
    PRIO1; MM8(0, 1); PRIO0; BAR;
    // ph2: reads aF-H1 (8); MM(1,0)
    LDA_H(0, 1);
    STAGE_B(0, 0, t2); STAGE_B(0, 64, t2);
    PRIO1; MM8(1, 0); PRIO0; BAR;
    // ph3: no reads; MM(1,1); tile boundary
    STAGE_B(0, 128, t2); STAGE_B(0, 192, t2);
    PRIO1; MM8(1, 1); PRIO0;
    if (it == NIT - 1) { VMCNT0; } else { VMCNT6; }   // t1's 8 landed
    BAR;
    // ph4: tile 2it+1
    LDA_H(1, 0); LDB_ALL(1);
    STAGE_A(0, 64, t2); STAGE_A(0, 192, t2);
    PRIO1; MM8(0, 0); PRIO0; BAR;
    // ph5
    STAGE_A(1, 0, t3); STAGE_A(1, 128, t3);
    PRIO1; MM8(0, 1); PRIO0; BAR;
    // ph6
    LDA_H(1, 1);
    STAGE_B(1, 0, t3); STAGE_B(1, 64, t3);
    PRIO1; MM8(1, 0); PRIO0; BAR;
    // ph7: boundary
    STAGE_B(1, 128, t3); STAGE_B(1, 192, t3);
    PRIO1; MM8(1, 1); PRIO0;
    VMCNT6;   // t2's 8 landed for next iter ph0
    BAR;
  }

  // ---- epilogue: LDS holds acc*rs; store applies *xs[row] + bias[col] ----
  float rsv[2];
#pragma unroll
  for (int nJ = 0; nJ < 2; ++nJ)
    rsv[nJ] = 1.0f / scale[n0 + wc * 64 + nJ * 32 + rl5];
  f32x4 bias4[8];
#pragma unroll
  for (int g = 0; g < 8; ++g)
    bias4[g] = *(const f32x4*)(bias + n0 + g * 32 + (lane & 7) * 4);

  float* ldsF = (float*)smem;
#pragma unroll
  for (int p = 0; p < 2; ++p) {
    if (p) BAR;                       // p1 writes wait for p0 stores
    // write phase: wave wr fills half wr, rows p*64..p*64+63 of its 128
#pragma unroll
    for (int mIh = 0; mIh < 2; ++mIh) {
      const int mI = p * 2 + mIh;
#pragma unroll
      for (int rg = 0; rg < 16; ++rg) {
        const int lrow = mIh * 32 + (rg & 3) + 8 * (rg >> 2) + 4 * hi;
        float* dst = ldsF + wr * EP_HALF + lrow * EP_PITCH + wc * 64 + rl5;
        dst[0]  = (float)acc[mI][0][rg] * rsv[0];
        dst[32] = (float)acc[mI][1][rg] * rsv[1];
      }
    }
    BAR;
    // store phase: 128B-contiguous per 8-lane group -> full L2 lines
    const int rr = wid * 8 + (lane >> 3);            // [0,64)
#pragma unroll
    for (int h = 0; h < 2; ++h) {
      const long grow = m0 + h * 128 + p * 64 + rr;
      const float xsr = xs[grow];
      const float* src = ldsF + h * EP_HALF + rr * EP_PITCH + (lane & 7) * 4;
      float* crow = C + grow * (long)FEATS + n0 + (lane & 7) * 4;
#pragma unroll
      for (int g = 0; g < 8; ++g) {
        f32x4 v = *(const f32x4*)(src + g * 32);
        *(f32x4*)(crow + g * 32) = v * xsr + bias4[g];
      }
    }
  }
}

// ---------------- fallback (ws too small): naive fp32 tiled GEMM ----------------
__global__ void naive_kernel(const float* __restrict__ x, const int* __restrict__ kq,
                             const float* __restrict__ scale, const float* __restrict__ bias,
                             float* __restrict__ out) {
  __shared__ float xa[16][16];
  __shared__ float wb[16][17];
  const int n = blockIdx.x * 16 + threadIdx.x;
  const int m = blockIdx.y * 16 + threadIdx.y;
  float accv = 0.f;
  for (int k0 = 0; k0 < D_IN; k0 += 16) {
    xa[threadIdx.y][threadIdx.x] = x[(long)m * D_IN + k0 + threadIdx.x];
    wb[threadIdx.y][threadIdx.x] = (float)kq[(long)(k0 + threadIdx.y) * FEATS + n];
    __syncthreads();
#pragma unroll
    for (int kk = 0; kk < 16; kk++) accv += xa[threadIdx.y][kk] * wb[kk][threadIdx.x];
    __syncthreads();
  }
  out[(long)m * FEATS + n] = accv * (1.0f / scale[n]) + bias[n];
}

extern "C" void kernel_launch(void* const* d_in, const int* in_sizes, int n_in,
                              void* d_out, int out_size, void* d_ws, size_t ws_size,
                              hipStream_t stream) {
  const float* x     = (const float*)d_in[0];
  const int*   kq    = (const int*)d_in[1];
  const float* scale = (const float*)d_in[2];
  const float* bias  = (const float*)d_in[3];
  float* out = (float*)d_out;

  const size_t need = (size_t)TOKENS * D_IN + (size_t)FEATS * D_IN + TOKENS * 4;
  if (ws_size < need) {
    naive_kernel<<<dim3(FEATS / 16, TOKENS / 16), dim3(16, 16), 0, stream>>>(
        x, kq, scale, bias, out);
    return;
  }

  signed char* Xq = (signed char*)d_ws;
  signed char* Wq = Xq + (size_t)TOKENS * D_IN;
  float* xs = (float*)(Wq + (size_t)FEATS * D_IN);

  quant_x_kernel<<<TOKENS, 256, 0, stream>>>(x, Xq, xs);
  wtrans8_kernel<<<dim3(FEATS / 64, D_IN / 64), dim3(256), 0, stream>>>(kq, Wq);
  gemm8i_kernel<<<dim3((TOKENS / 256) * (FEATS / 256)), 512, 0, stream>>>(
      Xq, Wq, xs, scale, bias, out);
}

// Round 12
// 602.773 us; speedup vs baseline: 1.2020x; 1.1016x over previous
//
#include <hip/hip_runtime.h>

#define TOKENS 8192
#define D_IN   4096
#define FEATS  16384
#define NT     (D_IN / 128)  // 32 K-tiles of 128 (i8)
#define NIT    (NT / 2)      // 16 iterations, 2 K-tiles each

typedef __attribute__((ext_vector_type(4))) int   i4v;
typedef __attribute__((ext_vector_type(4))) float f32x4;

__device__ __forceinline__ void gload_lds16(const void* g, void* l) {
  __builtin_amdgcn_global_load_lds(
      (const __attribute__((address_space(1))) void*)g,
      (__attribute__((address_space(3))) void*)l, 16, 0, 0);
}

// ---------------- pre-pass A: x fp32 -> int8 with per-row scale ----------------
__device__ __forceinline__ int pack4(float4 f, float inv) {
  int a = __float2int_rn(f.x * inv), b = __float2int_rn(f.y * inv),
      c = __float2int_rn(f.z * inv), d = __float2int_rn(f.w * inv);
  return (a & 0xff) | ((b & 0xff) << 8) | ((c & 0xff) << 16) | ((d & 0xff) << 24);
}

__global__ __launch_bounds__(256) void quant_x_kernel(const float* __restrict__ x,
                                                      signed char* __restrict__ xq,
                                                      float* __restrict__ xs) {
  const int row = blockIdx.x, t = threadIdx.x;
  const float* xr = x + (long)row * D_IN;
  float4 v0 = *(const float4*)(xr + t * 16 + 0);
  float4 v1 = *(const float4*)(xr + t * 16 + 4);
  float4 v2 = *(const float4*)(xr + t * 16 + 8);
  float4 v3 = *(const float4*)(xr + t * 16 + 12);
  float m = 0.f;
  m = fmaxf(m, fmaxf(fmaxf(fabsf(v0.x), fabsf(v0.y)), fmaxf(fabsf(v0.z), fabsf(v0.w))));
  m = fmaxf(m, fmaxf(fmaxf(fabsf(v1.x), fabsf(v1.y)), fmaxf(fabsf(v1.z), fabsf(v1.w))));
  m = fmaxf(m, fmaxf(fmaxf(fabsf(v2.x), fabsf(v2.y)), fmaxf(fabsf(v2.z), fabsf(v2.w))));
  m = fmaxf(m, fmaxf(fmaxf(fabsf(v3.x), fabsf(v3.y)), fmaxf(fabsf(v3.z), fabsf(v3.w))));
#pragma unroll
  for (int off = 32; off >= 1; off >>= 1) m = fmaxf(m, __shfl_xor(m, off));
  __shared__ float wm[4];
  if ((t & 63) == 0) wm[t >> 6] = m;
  __syncthreads();
  m = fmaxf(fmaxf(wm[0], wm[1]), fmaxf(wm[2], wm[3]));
  m = fmaxf(m, 1e-20f);
  const float inv = 127.f / m;
  if (t == 0) xs[row] = m / 127.f;
  int4 o;
  o.x = pack4(v0, inv); o.y = pack4(v1, inv);
  o.z = pack4(v2, inv); o.w = pack4(v3, inv);
  *(int4*)(xq + (long)row * D_IN + t * 16) = o;
}

// ---------------- pre-pass B: kernel int32 [K][N] -> int8 Wq [N][K] ----------------
// 128k x 64n tile so each [N][K] output row segment is a FULL 128 B line.
__global__ __launch_bounds__(256) void wtrans8_kernel(const int* __restrict__ kq,
                                                      signed char* __restrict__ wt) {
  __shared__ signed char tile[128][68];   // pitch 68 (17 words) -> store-phase reads spread
  const int n0 = blockIdx.x * 64, k0 = blockIdx.y * 128;
  const int t = threadIdx.x;
  // load: thread t covers k-row (t>>4)+16p, 4 ints at nc
  const int kr = t >> 4, nc = (t & 15) * 4;
#pragma unroll
  for (int p = 0; p < 8; p++) {
    int4 v = *(const int4*)(kq + (long)(k0 + kr + 16 * p) * FEATS + n0 + nc);
    signed char* dst = &tile[kr + 16 * p][nc];
    dst[0] = (signed char)v.x; dst[1] = (signed char)v.y;
    dst[2] = (signed char)v.z; dst[3] = (signed char)v.w;
  }
  __syncthreads();
  // store: thread t covers n-row t>>2, k-bytes (t&3)*32 .. +31 (two int4 stores)
  const int n = t >> 2, kc = (t & 3) * 32;
  int w[8];
#pragma unroll
  for (int g = 0; g < 8; g++) {
    const int kb = kc + g * 4;
    w[g] = (tile[kb + 0][n] & 0xff)        | ((tile[kb + 1][n] & 0xff) << 8) |
           ((tile[kb + 2][n] & 0xff) << 16) | ((tile[kb + 3][n] & 0xff) << 24);
  }
  signed char* out = wt + (long)(n0 + n) * D_IN + k0 + kc;
  *(int4*)(out)      = make_int4(w[0], w[1], w[2], w[3]);
  *(int4*)(out + 16) = make_int4(w[4], w[5], w[6], w[7]);
}

// ---------------- main GEMM: 256x256 tile, BK=128 i8, r6 schedule (best measured) ----------------
#define BAR        __builtin_amdgcn_s_barrier()
#define VMCNT6     asm volatile("s_waitcnt vmcnt(6)" ::: "memory")
#define VMCNT0     asm volatile("s_waitcnt vmcnt(0)" ::: "memory")
#define PRIO1      __builtin_amdgcn_s_setprio(1)
#define PRIO0      __builtin_amdgcn_s_setprio(0)

// tile bases inside smem: buf B_ in {0,1}, MAT 0=A 1=B; each tile 256x128 B
#define TILEBASE(B_, MAT) (smem + (B_) * 65536 + (MAT) * 32768)

// stage one 64-row quarter (8 KiB) of A or B for K-tile KT into buf B_
#define STAGE_A(B_, R0, KT) do { if ((KT) < NT) \
  gload_lds16(Xq + (m0 + (R0) + sr) * (long)D_IN + (long)(KT) * 128 + sgb, \
              TILEBASE(B_, 0) + (R0) * 128 + wid * 1024); } while (0)
#define STAGE_B(B_, R0, KT) do { if ((KT) < NT) \
  gload_lds16(Wq + (n0 + (R0) + sr) * (long)D_IN + (long)(KT) * 128 + sgb, \
              TILEBASE(B_, 1) + (R0) * 128 + wid * 1024); } while (0)

// swizzled fragment reads (ks=0,1 packed per call)
#define LDA1(B_, I) do { \
  const char* _p = TILEBASE(B_, 0) + (wr * 128 + (I) * 16 + rl) * 128; \
  aF[(I) & 3][0] = *(const i4v*)(_p + koff0); \
  aF[(I) & 3][1] = *(const i4v*)(_p + koff1); } while (0)
#define LDA4(B_, H) do { LDA1(B_, (H)*4+0); LDA1(B_, (H)*4+1); LDA1(B_, (H)*4+2); LDA1(B_, (H)*4+3); } while (0)
#define LDB1(B_, J) do { \
  const char* _p = TILEBASE(B_, 1) + (wc * 64 + (J) * 16 + rl) * 128; \
  bF[J][0] = *(const i4v*)(_p + koff0); \
  bF[J][1] = *(const i4v*)(_p + koff1); } while (0)
#define LDB4(B_) do { LDB1(B_, 0); LDB1(B_, 1); LDB1(B_, 2); LDB1(B_, 3); } while (0)

#define MM1(I, J, KS) \
  acc[I][J] = __builtin_amdgcn_mfma_i32_16x16x64_i8(aF[(I) & 3][KS], bF[J][KS], acc[I][J], 0, 0, 0)
#define MM16(H, JH) do { \
  MM1((H)*4+0,(JH)*2+0,0); MM1((H)*4+0,(JH)*2+0,1); \
  MM1((H)*4+0,(JH)*2+1,0); MM1((H)*4+0,(JH)*2+1,1); \
  MM1((H)*4+1,(JH)*2+0,0); MM1((H)*4+1,(JH)*2+0,1); \
  MM1((H)*4+1,(JH)*2+1,0); MM1((H)*4+1,(JH)*2+1,1); \
  MM1((H)*4+2,(JH)*2+0,0); MM1((H)*4+2,(JH)*2+0,1); \
  MM1((H)*4+2,(JH)*2+1,0); MM1((H)*4+2,(JH)*2+1,1); \
  MM1((H)*4+3,(JH)*2+0,0); MM1((H)*4+3,(JH)*2+0,1); \
  MM1((H)*4+3,(JH)*2+1,0); MM1((H)*4+3,(JH)*2+1,1); } while (0)

// epilogue LDS layout: 2 halves x 64 rows x pitch 1040B (260 f32) = 133120 B
#define EP_PITCH 260
#define EP_HALF  (64 * EP_PITCH)

__global__ __launch_bounds__(512, 2) void gemm8i_kernel(
    const signed char* __restrict__ Xq,      // [M][K] i8
    const signed char* __restrict__ Wq,      // [N][K] i8
    const float* __restrict__ xs,            // [M] per-row x scale
    const float* __restrict__ scale,         // [N]
    const float* __restrict__ bias,          // [N]
    float* __restrict__ C) {
  // max(main 131072, epilogue 133120)
  __shared__ __attribute__((aligned(16))) char smem[133120];

  const int tid = threadIdx.x;
  const int lane = tid & 63, wid = tid >> 6;
  const int wr = wid >> 2, wc = wid & 3;       // 2 x 4 wave grid, each 128x64 out
  const int rl = lane & 15, q = lane >> 4;

  // L2-sharing map: per-XCD resident set = 4m x 8n rectangle (m-fastest)
  const int bid  = blockIdx.x;
  const int xcd  = bid & 7;
  const int l    = bid >> 3;          // [0,256)
  const int rect = l >> 5;            // [0,8)  n-octant
  const int r    = l & 31;
  const int mloc = r & 3;
  const int nl   = r >> 2;            // [0,8)
  const long m0 = (long)(xcd * 4 + mloc) * 256;
  const long n0 = (long)(rect * 8 + nl) * 256;

  // staging: thread t covers row sr, 16B granule (t&7), source pre-swizzled (rule 21)
  const int sr = tid >> 3;
  const int sgb = ((tid & 7) ^ (sr & 7)) * 16;  // byte offset within 128B row

  // read-side swizzle: byte ^= ((row&7)<<4)
  const int xm = (rl & 7) << 4;
  const int koff0 = (q * 16) ^ xm;              // ks=0 (k 0..63)
  const int koff1 = (64 + q * 16) ^ xm;         // ks=1 (k 64..127)

  i4v acc[8][4] = {};
  i4v aF[4][2], bF[4][2];

  // ---- prologue: tile0 full (8 quarters) + tile1 {B x4, A-q0, A-q2} (6) ----
  STAGE_B(0, 0, 0); STAGE_B(0, 64, 0); STAGE_B(0, 128, 0); STAGE_B(0, 192, 0);
  STAGE_A(0, 0, 0); STAGE_A(0, 64, 0); STAGE_A(0, 128, 0); STAGE_A(0, 192, 0);
  STAGE_B(1, 0, 1); STAGE_B(1, 64, 1); STAGE_B(1, 128, 1); STAGE_B(1, 192, 1);
  STAGE_A(1, 0, 1); STAGE_A(1, 128, 1);
  VMCNT6;   // tile0's 8 landed; tile1's 6 in flight
  BAR;

  // r6 schedule: clumped reads {16,0,8,0}, 1 barrier/phase, no asm lgkm
  // (compiler emits fine-grained partial lgkm waits per consumed fragment).
  // Stage plan: ph0: t1 A-q1,q3 | ph1: t2 A-q0,q2 | ph2: t2 B-q0,q1
  //             ph3: t2 B-q2,q3 | ph4: t2 A-q1,q3 | ph5: t3 A-q0,q2
  //             ph6: t3 B-q0,q1 | ph7: t3 B-q2,q3
  for (int it = 0; it < NIT; ++it) {
    const int t1 = 2 * it + 1, t2 = 2 * it + 2, t3 = 2 * it + 3;
    // ph0: reads aF-H0 + bF all (16); MM(0,0)
    LDA4(0, 0); LDB4(0);
    STAGE_A(1, 64, t1); STAGE_A(1, 192, t1);
    PRIO1; MM16(0, 0); PRIO0; BAR;
    // ph1: no reads; MM(0,1)
    STAGE_A(0, 0, t2); STAGE_A(0, 128, t2);
    PRIO1; MM16(0, 1); PRIO0; BAR;
    // ph2: reads aF-H1 (8); MM(1,0)
    LDA4(0, 1);
    STAGE_B(0, 0, t2); STAGE_B(0, 64, t2);
    PRIO1; MM16(1, 0); PRIO0; BAR;
    // ph3: no reads; MM(1,1); tile boundary
    STAGE_B(0, 128, t2); STAGE_B(0, 192, t2);
    PRIO1; MM16(1, 1); PRIO0;
    if (it == NIT - 1) { VMCNT0; } else { VMCNT6; }   // t1's 8 landed
    BAR;
    // ph4: tile 2it+1
    LDA4(1, 0); LDB4(1);
    STAGE_A(0, 64, t2); STAGE_A(0, 192, t2);
    PRIO1; MM16(0, 0); PRIO0; BAR;
    // ph5
    STAGE_A(1, 0, t3); STAGE_A(1, 128, t3);
    PRIO1; MM16(0, 1); PRIO0; BAR;
    // ph6
    LDA4(1, 1);
    STAGE_B(1, 0, t3); STAGE_B(1, 64, t3);
    PRIO1; MM16(1, 0); PRIO0; BAR;
    // ph7: boundary
    STAGE_B(1, 128, t3); STAGE_B(1, 192, t3);
    PRIO1; MM16(1, 1); PRIO0;
    VMCNT6;   // t2's 8 landed for next iter ph0
    BAR;
  }

  // ---- epilogue: full-line C stores via LDS transpose (kills write RMW) ----
  // y = acc * xs[row] * (1/scale[col]) + bias[col]
  float rsv[4], bvv[4];
#pragma unroll
  for (int j = 0; j < 4; j++) {
    const long col = n0 + wc * 64 + j * 16 + rl;
    rsv[j] = 1.0f / scale[col];
    bvv[j] = bias[col];
  }
  float* ldsF = (float*)smem;
#pragma unroll
  for (int p = 0; p < 2; ++p) {
    if (p) BAR;                       // p1 writes wait for p0 stores
    // write phase: wave wr fills half wr, rows lrow = i*16+q*4+r2
#pragma unroll
    for (int i = 0; i < 4; ++i) {
      const int ii = p * 4 + i;
      const long grow0 = m0 + wr * 128 + ii * 16 + q * 4;
#pragma unroll
      for (int r2 = 0; r2 < 4; ++r2) {
        const float xv = xs[grow0 + r2];
        const int lrow = i * 16 + q * 4 + r2;
        float* dst = ldsF + wr * EP_HALF + lrow * EP_PITCH;
#pragma unroll
        for (int j = 0; j < 4; ++j)
          dst[wc * 64 + j * 16 + rl] = (float)acc[ii][j][r2] * xv * rsv[j] + bvv[j];
      }
    }
    BAR;
    // store phase: 128B-contiguous per 8-lane group -> full L2 lines
#pragma unroll
    for (int h = 0; h < 2; ++h) {
      const int rr = wid * 8 + (lane >> 3);          // [0,64)
      const long grow = m0 + h * 128 + p * 64 + rr;
      const float* src = ldsF + h * EP_HALF + rr * EP_PITCH + (lane & 7) * 4;
      float* crow = C + grow * (long)FEATS + n0 + (lane & 7) * 4;
#pragma unroll
      for (int g = 0; g < 8; ++g) {
        f32x4 v = *(const f32x4*)(src + g * 32);
        *(f32x4*)(crow + g * 32) = v;
      }
    }
  }
}

// ---------------- fallback (ws too small): naive fp32 tiled GEMM ----------------
__global__ void naive_kernel(const float* __restrict__ x, const int* __restrict__ kq,
                             const float* __restrict__ scale, const float* __restrict__ bias,
                             float* __restrict__ out) {
  __shared__ float xa[16][16];
  __shared__ float wb[16][17];
  const int n = blockIdx.x * 16 + threadIdx.x;
  const int m = blockIdx.y * 16 + threadIdx.y;
  float accv = 0.f;
  for (int k0 = 0; k0 < D_IN; k0 += 16) {
    xa[threadIdx.y][threadIdx.x] = x[(long)m * D_IN + k0 + threadIdx.x];
    wb[threadIdx.y][threadIdx.x] = (float)kq[(long)(k0 + threadIdx.y) * FEATS + n];
    __syncthreads();
#pragma unroll
    for (int kk = 0; kk < 16; kk++) accv += xa[threadIdx.y][kk] * wb[kk][threadIdx.x];
    __syncthreads();
  }
  out[(long)m * FEATS + n] = accv * (1.0f / scale[n]) + bias[n];
}

extern "C" void kernel_launch(void* const* d_in, const int* in_sizes, int n_in,
                              void* d_out, int out_size, void* d_ws, size_t ws_size,
                              hipStream_t stream) {
  const float* x     = (const float*)d_in[0];
  const int*   kq    = (const int*)d_in[1];
  const float* scale = (const float*)d_in[2];
  const float* bias  = (const float*)d_in[3];
  float* out = (float*)d_out;

  const size_t need = (size_t)TOKENS * D_IN + (size_t)FEATS * D_IN + TOKENS * 4;
  if (ws_size < need) {
    naive_kernel<<<dim3(FEATS / 16, TOKENS / 16), dim3(16, 16), 0, stream>>>(
        x, kq, scale, bias, out);
    return;
  }

  signed char* Xq = (signed char*)d_ws;
  signed char* Wq = Xq + (size_t)TOKENS * D_IN;
  float* xs = (float*)(Wq + (size_t)FEATS * D_IN);

  quant_x_kernel<<<TOKENS, 256, 0, stream>>>(x, Xq, xs);
  wtrans8_kernel<<<dim3(FEATS / 64, D_IN / 128), dim3(256), 0, stream>>>(kq, Wq);
  gemm8i_kernel<<<dim3((TOKENS / 256) * (FEATS / 256)), 512, 0, stream>>>(
      Xq, Wq, xs, scale, bias, out);
}